// Round 3
// baseline (503.937 us; speedup 1.0000x reference)
//
#include <hip/hip_runtime.h>
#include <hip/hip_cooperative_groups.h>
#include <math.h>

namespace cg = cooperative_groups;

// LRU scan: h[b,t,d] = lam[d]*h[b,t-1,d] + gam[d]*x[b,t,d], inclusive over t.
// lam = exp(-exp(nu_logs)), gam = sqrt(1-lam^2).
// Single cooperative kernel, 3 phases separated by grid.sync():
//   phase1: per-chunk aggregate (h=0 seed) -> carry[b,c,d]   (reads x, streams into L2/L3)
//   phase2: parallel Kogge-Stone scan of carries along c (LDS), weight lam^L
//           iteratively squared; writes back EXCLUSIVE carries.
//   phase3: seeded per-chunk scan by the SAME thread as phase1 (x re-read is
//           same-XCD L2/L3-hot), writes output.

#define B_  4
#define I_  8192
#define D_  1024
#define C_  256           // chunks along time
#define L_  32            // I_ / C_
#define D4  (D_ / 4)      // float4 groups along d
#define NBLK (B_ * C_ * D4 / 256)   // 1024 blocks, 4/CU -> fully co-resident

__device__ __forceinline__ void load_lam_gam(const float* __restrict__ nu_logs,
                                             int d4, float4& lam, float4& gam) {
    const float* nl = nu_logs + d4 * 4;
    lam.x = expf(-expf(nl[0]));
    lam.y = expf(-expf(nl[1]));
    lam.z = expf(-expf(nl[2]));
    lam.w = expf(-expf(nl[3]));
    gam.x = sqrtf(1.0f - lam.x * lam.x);
    gam.y = sqrtf(1.0f - lam.y * lam.y);
    gam.z = sqrtf(1.0f - lam.z * lam.z);
    gam.w = sqrtf(1.0f - lam.w * lam.w);
}

__global__ __launch_bounds__(256) void lru_fused(const float4* __restrict__ x,
                                                 const float* __restrict__ nu_logs,
                                                 float4* __restrict__ carry,
                                                 float4* __restrict__ out) {
    cg::grid_group grid = cg::this_grid();

    const int tid = blockIdx.x * 256 + threadIdx.x;   // 0 .. 262143
    const int d4 = tid & (D4 - 1);                    // coalesced along d
    const int c  = (tid >> 8) & (C_ - 1);
    const int b  = tid >> 16;

    float4 lam, gam;
    load_lam_gam(nu_logs, d4, lam, gam);

    const int idx0 = (b * I_ + c * L_) * D4 + d4;
    const int cidx = (b * C_ + c) * D4 + d4;

    // ---- phase 1: chunk aggregate with h = 0 ----
    {
        float4 h = {0.f, 0.f, 0.f, 0.f};
        int idx = idx0;
#pragma unroll 8
        for (int t = 0; t < L_; ++t) {
            float4 v = x[idx];
            h.x = fmaf(lam.x, h.x, gam.x * v.x);
            h.y = fmaf(lam.y, h.y, gam.y * v.y);
            h.z = fmaf(lam.z, h.z, gam.z * v.z);
            h.w = fmaf(lam.w, h.w, gam.w * v.w);
            idx += D4;
        }
        carry[cidx] = h;
    }

    grid.sync();

    // ---- phase 2: weighted Kogge-Stone over chunks, one block per (b, d4) ----
    {
        __shared__ float4 buf[C_];                    // 4 KiB
        const int c2  = threadIdx.x;
        const int d42 = blockIdx.x & (D4 - 1);
        const int b2  = blockIdx.x >> 8;

        const float* nl = nu_logs + d42 * 4;
        float4 p;                                     // lam^L, squared each step
        p.x = expf(-expf(nl[0]) * (float)L_);
        p.y = expf(-expf(nl[1]) * (float)L_);
        p.z = expf(-expf(nl[2]) * (float)L_);
        p.w = expf(-expf(nl[3]) * (float)L_);

        const int gidx = (b2 * C_ + c2) * D4 + d42;
        float4 val = carry[gidx];
        buf[c2] = val;

        for (int off = 1; off < C_; off <<= 1) {
            __syncthreads();
            float4 prev = (c2 >= off) ? buf[c2 - off] : make_float4(0.f, 0.f, 0.f, 0.f);
            __syncthreads();
            if (c2 >= off) {
                val.x = fmaf(p.x, prev.x, val.x);
                val.y = fmaf(p.y, prev.y, val.y);
                val.z = fmaf(p.z, prev.z, val.z);
                val.w = fmaf(p.w, prev.w, val.w);
                buf[c2] = val;
            }
            p.x *= p.x; p.y *= p.y; p.z *= p.z; p.w *= p.w;
        }
        __syncthreads();
        float4 excl = (c2 == 0) ? make_float4(0.f, 0.f, 0.f, 0.f) : buf[c2 - 1];
        carry[gidx] = excl;
    }

    grid.sync();

    // ---- phase 3: seeded scan, same thread re-reads its own x chunk ----
    {
        float4 h = carry[cidx];                       // exclusive carry
        int idx = idx0;
#pragma unroll 8
        for (int t = 0; t < L_; ++t) {
            float4 v = x[idx];
            h.x = fmaf(lam.x, h.x, gam.x * v.x);
            h.y = fmaf(lam.y, h.y, gam.y * v.y);
            h.z = fmaf(lam.z, h.z, gam.z * v.z);
            h.w = fmaf(lam.w, h.w, gam.w * v.w);
            out[idx] = h;
            idx += D4;
        }
    }
}

extern "C" void kernel_launch(void* const* d_in, const int* in_sizes, int n_in,
                              void* d_out, int out_size, void* d_ws, size_t ws_size,
                              hipStream_t stream) {
    const float4* x       = (const float4*)d_in[0];   // [B, I, D] fp32
    const float*  nu_logs = (const float*)d_in[1];    // [D] fp32
    float4*       out     = (float4*)d_out;           // [B, I, D] fp32
    float4*       carry   = (float4*)d_ws;            // B_*C_*D_ floats = 4 MiB

    void* args[] = {(void*)&x, (void*)&nu_logs, (void*)&carry, (void*)&out};
    hipLaunchCooperativeKernel((void*)lru_fused, dim3(NBLK), dim3(256),
                               args, 0, stream);
}